// Round 1
// baseline (205.988 us; speedup 1.0000x reference)
//
#include <hip/hip_runtime.h>

// Spiking basal ganglia: T=512 serial LIF steps, B=256 circuits.
// R6: async producer pipeline. R5 post-mortem: VALUBusy 11.8% == consumer-only
// => producers are the wall. Their structure was burst-16-loads + __syncthreads
// (vmcnt drains to 0 every chunk) => memory duty-cycled at ~1.25 TB/s device
// effective (765 GB/s HBM). Fix (T3/T4 pattern): producers issue
// global_load_lds dwordx4 straight into a 4-deep ring of RAW noise chunks,
// staying 3 chunks ahead, with raw s_barrier + counted s_waitcnt vmcnt(16)
// (never 0 in steady state) so 2 chunks of loads stay in flight ACROSS every
// barrier. Consumer computes I = (x.W)*mod + noise*0.1 inline with the EXACT
// op sequence of the R2..R5 bit-exact kernels (contract off, fma dot).

typedef const __attribute__((address_space(1))) void* gptr1_t;
typedef __attribute__((address_space(3))) void* lptr3_t;

__device__ __forceinline__ void gload_lds16(const float* g, float* l) {
    __builtin_amdgcn_global_load_lds((gptr1_t)g, (lptr3_t)l, 16, 0, 0);
}

__global__ __launch_bounds__(320, 1) void bg_kernel(
    const float* __restrict__ x,      // [T,B,2]
    const float* __restrict__ dopa,   // [T,B]
    const float* __restrict__ Wd1,    // [128,2]
    const float* __restrict__ Wd2,    // [128,2]
    const float* __restrict__ nd1,    // [T,B,128]
    const float* __restrict__ nd2,    // [T,B,128]
    float* __restrict__ out)          // [T,B]
{
#pragma clang fp contract(off)
    constexpr int T = 512, B = 256;
    constexpr int S = 32;             // steps per chunk
    constexpr int NCH = T / S;        // 16 chunks
    constexpr int NBUF = 4;           // ring depth
    constexpr size_t TSTRIDE = (size_t)B * 128;   // noise t-stride (floats)

    // raw noise ring: [buf][step][0..127]=nd1 row, [128..255]=nd2 row. 128 KB.
    __shared__ float lds_raw[NBUF][S][256];
    __shared__ float lds_x[T][2];          // 4 KB
    __shared__ float lds_d[T];             // 2 KB

    const int b    = blockIdx.x;
    const int tid  = threadIdx.x;
    const int wv   = tid >> 6;        // 0 = consumer, 1..4 = producers
    const int lane = tid & 63;

    // ---- prologue A: stage x/dopa (all 320 threads) ----
    for (int t = tid; t < T; t += 320) {
        const float2 xv = *(const float2*)(x + (size_t)t * (B * 2) + b * 2);
        lds_x[t][0] = xv.x;
        lds_x[t][1] = xv.y;
        lds_d[t]    = dopa[(size_t)t * B + b];
    }
    __syncthreads();

    if (wv == 0) {
        // ================= CONSUMER =================
        // lane n owns neurons {2n, 2n+1} of both populations (same mapping as
        // the R2..R5 producer lanes): W rows 2n,2n+1 -> one float4 each.
        const float4 w1 = *(const float4*)(Wd1 + 4 * lane);
        const float4 w2 = *(const float4*)(Wd2 + 4 * lane);

        __syncthreads();   // matches producers' prologue s_barrier

        float v1a = 0.0f, v1b = 0.0f;
        float v2a = 0.0f, v2b = 0.0f;
        float v_stn = 0.0f, v_gpi = 0.0f;
        float gate_reg = 0.0f;

        for (int i = 0; i < NCH; ++i) {
            const float (*buf)[256] = lds_raw[i & (NBUF - 1)];

#pragma unroll
            for (int s = 0; s < S; ++s) {
                const int t = i * S + s;
                const float2 a1 = *(const float2*)&buf[s][2 * lane];
                const float2 a2 = *(const float2*)&buf[s][128 + 2 * lane];
                const float xx  = lds_x[t][0], xy = lds_x[t][1];
                const float dop = lds_d[t];

                // ---- bit-identical I computation (R2..R5 op order) ----
                const float m1 = 1.0f + dop * 0.5f;
                const float m2 = 1.0f - dop * 0.3f;
                const float dot1a = __builtin_fmaf(xy, w1.y, xx * w1.x);
                const float dot1b = __builtin_fmaf(xy, w1.w, xx * w1.z);
                const float dot2a = __builtin_fmaf(xy, w2.y, xx * w2.x);
                const float dot2b = __builtin_fmaf(xy, w2.w, xx * w2.z);
                const float Ix = dot1a * m1 + a1.x * 0.1f;
                const float Iy = dot1b * m1 + a1.y * 0.1f;
                const float Iz = dot2a * m2 + a2.x * 0.1f;
                const float Iw = dot2b * m2 + a2.y * 0.1f;

                // ---- bit-identical recurrence (R2..R5 verified) ----
                v1a = 0.8f * v1a + 0.2f * Ix;
                v1b = 0.8f * v1b + 0.2f * Iy;
                v2a = 0.8f * v2a + 0.2f * Iz;
                v2b = 0.8f * v2b + 0.2f * Iw;

                const bool s1a = v1a >= 0.5f, s1b = v1b >= 0.5f;
                const bool s2a = v2a >= 0.5f, s2b = v2b >= 0.5f;
                v1a = s1a ? 0.0f : v1a;
                v1b = s1b ? 0.0f : v1b;
                v2a = s2a ? 0.0f : v2a;
                v2b = s2b ? 0.0f : v2b;

                const int c1 = __popcll(__ballot(s1a)) + __popcll(__ballot(s1b));
                const int c2 = __popcll(__ballot(s2a)) + __popcll(__ballot(s2b));
                const float mean1 = (float)c1 * 0.0078125f;
                const float mean2 = (float)c2 * 0.0078125f;

                const float I_stn = mean2 * 0.5f;
                v_stn = 0.8f * v_stn + 0.2f * I_stn;
                const float s_stn = (v_stn >= 0.5f) ? 1.0f : 0.0f;
                v_stn = (v_stn >= 0.5f) ? 0.0f : v_stn;

                const float I_gpi = (0.4f + mean1 * -0.8f) + s_stn * 0.6f;
                v_gpi = 0.8f * v_gpi + 0.2f * I_gpi;
                const float s_gpi = (v_gpi >= 0.5f) ? 1.0f : 0.0f;
                v_gpi = (v_gpi >= 0.5f) ? 0.0f : v_gpi;

                const float gate = mean1 - s_gpi;   // wave-uniform

                // lane ((i&1)*32 + s) latches step i*32+s's gate
                const int latch = ((i & 1) << 5) | s;
                gate_reg = (lane == latch) ? gate : gate_reg;
            }

            if (i & 1) {
                const int t0 = (i - 1) * S;
                out[(size_t)(t0 + lane) * B + b] = gate_reg;
            }

            __syncthreads();
        }
    } else {
        // ================= PRODUCERS (waves 1..4) =================
        // Pure issue engines: 8 global_load_lds (1 KB each) per chunk per
        // wave. Lanes 0..31 fetch the nd1 row (16 B/lane), lanes 32..63 the
        // nd2 row; LDS dest is wave-uniform base + lane*16 (linear, m104).
        const int p0 = (wv - 1) * 8;   // this wave covers steps p0..p0+7
        const float* srcb = (lane < 32)
            ? (nd1 + (size_t)b * 128 + 4 * lane)
            : (nd2 + (size_t)b * 128 + 4 * (lane - 32));

        auto stage = [&](int c) {
            float* dst = &lds_raw[c & (NBUF - 1)][0][0];
#pragma unroll
            for (int k = 0; k < 8; ++k) {
                const int s = p0 + k;
                const int t = c * S + s;
                gload_lds16(srcb + (size_t)t * TSTRIDE, dst + (size_t)s * 256);
            }
        };

        // prologue B: run 3 chunks ahead; chunk 0 must be complete at barrier
        stage(0);
        stage(1);
        stage(2);
        __builtin_amdgcn_sched_barrier(0);
        asm volatile("s_waitcnt vmcnt(16)" ::: "memory");   // chunk 0 done
        __builtin_amdgcn_sched_barrier(0);
        __builtin_amdgcn_s_barrier();
        __builtin_amdgcn_sched_barrier(0);

        for (int i = 0; i < NCH; ++i) {
            if (i + 3 < NCH) stage(i + 3);
            __builtin_amdgcn_sched_barrier(0);
            // Before barrier i, chunk i+1 must be complete (consumer reads it
            // next iteration). In-flight allowed: chunks i+2, i+3 -> 16.
            if (i <= 12) {
                asm volatile("s_waitcnt vmcnt(16)" ::: "memory");
            } else if (i == 13) {
                asm volatile("s_waitcnt vmcnt(8)" ::: "memory");  // only ch15 in flight
            } else if (i == 14) {
                asm volatile("s_waitcnt vmcnt(0)" ::: "memory");  // ch15 done
            }
            __builtin_amdgcn_sched_barrier(0);
            __builtin_amdgcn_s_barrier();
            __builtin_amdgcn_sched_barrier(0);
        }
    }
}

extern "C" void kernel_launch(void* const* d_in, const int* in_sizes, int n_in,
                              void* d_out, int out_size, void* d_ws, size_t ws_size,
                              hipStream_t stream) {
    const float* x    = (const float*)d_in[0];
    const float* dopa = (const float*)d_in[1];
    // d_in[2] = rpe — unused by the reference
    const float* Wd1  = (const float*)d_in[3];
    const float* Wd2  = (const float*)d_in[4];
    const float* nd1  = (const float*)d_in[5];
    const float* nd2  = (const float*)d_in[6];
    float* out = (float*)d_out;

    bg_kernel<<<dim3(256), dim3(320), 0, stream>>>(x, dopa, Wd1, Wd2, nd1, nd2, out);
}

// Round 4
// 192.727 us; speedup vs baseline: 1.0688x; 1.0688x over previous
//
#include <hip/hip_runtime.h>

// Spiking basal ganglia: T=512 serial LIF steps, B=256 circuits.
// R9: R5's verified structure (ran at 102us), ONE variable changed: 8
// producer waves instead of 4 (576-thread block, each wave covers 4
// steps/chunk). R7/R8 (inline-asm barrier pipeline) hit "container failed
// twice" two rounds running -- cannot rule out that the exotic barrier loop
// hangs the box, so this round uses ONLY constructs that already passed:
// plain __syncthreads, plain register loads, triple-buffered LDS ring.
// Theory under test: per-wave load-service concurrency is the limiter
// (R3 1 wave: 2.7 GB/s/blk -> R5 4 waves: 5.1, same bytes-in-flight);
// doubling request sources to 8 waves should land ~55-70us.

__global__ __launch_bounds__(576, 1) void bg_kernel(
    const float* __restrict__ x,      // [T,B,2]
    const float* __restrict__ dopa,   // [T,B]
    const float* __restrict__ Wd1,    // [128,2]
    const float* __restrict__ Wd2,    // [128,2]
    const float* __restrict__ nd1,    // [T,B,128]
    const float* __restrict__ nd2,    // [T,B,128]
    float* __restrict__ out)          // [T,B]
{
#pragma clang fp contract(off)
    constexpr int T = 512, B = 256;
    constexpr int S = 32;             // steps per chunk
    constexpr int NCH = T / S;        // 16 chunks
    constexpr size_t TSTRIDE = (size_t)B * 128;   // noise t-stride (floats)

    __shared__ float lds_I[3][S][64][4];   // 96 KB: triple-buffered currents
    __shared__ float lds_x[T][2];          // 4 KB
    __shared__ float lds_d[T];             // 2 KB

    const int b    = blockIdx.x;
    const int tid  = threadIdx.x;
    const int wv   = tid >> 6;        // 0 = consumer, 1..8 = producers
    const int lane = tid & 63;

    // ---- prologue A: stage x/dopa (all 576 threads) ----
    for (int t = tid; t < T; t += 576) {
        const float2 xv = *(const float2*)(x + (size_t)t * (B * 2) + b * 2);
        lds_x[t][0] = xv.x;
        lds_x[t][1] = xv.y;
        lds_d[t]    = dopa[(size_t)t * B + b];
    }
    __syncthreads();

    if (wv == 0) {
        // ================= CONSUMER (identical to R5's verified form) ======
        __syncthreads();   // matches producers' prologue-B barrier

        float v1a = 0.0f, v1b = 0.0f;
        float v2a = 0.0f, v2b = 0.0f;
        float v_stn = 0.0f, v_gpi = 0.0f;
        float gate_reg = 0.0f;

        for (int i = 0; i < NCH; ++i) {
            const float (*buf)[64][4] = lds_I[i % 3];

#pragma unroll
            for (int s = 0; s < S; ++s) {
                const float4 I = *(const float4*)&buf[s][lane][0];

                // ---- bit-identical recurrence (R2..R5 verified) ----
                v1a = 0.8f * v1a + 0.2f * I.x;
                v1b = 0.8f * v1b + 0.2f * I.y;
                v2a = 0.8f * v2a + 0.2f * I.z;
                v2b = 0.8f * v2b + 0.2f * I.w;

                const bool s1a = v1a >= 0.5f, s1b = v1b >= 0.5f;
                const bool s2a = v2a >= 0.5f, s2b = v2b >= 0.5f;
                v1a = s1a ? 0.0f : v1a;
                v1b = s1b ? 0.0f : v1b;
                v2a = s2a ? 0.0f : v2a;
                v2b = s2b ? 0.0f : v2b;

                const int c1 = __popcll(__ballot(s1a)) + __popcll(__ballot(s1b));
                const int c2 = __popcll(__ballot(s2a)) + __popcll(__ballot(s2b));
                const float mean1 = (float)c1 * 0.0078125f;
                const float mean2 = (float)c2 * 0.0078125f;

                const float I_stn = mean2 * 0.5f;
                v_stn = 0.8f * v_stn + 0.2f * I_stn;
                const float s_stn = (v_stn >= 0.5f) ? 1.0f : 0.0f;
                v_stn = (v_stn >= 0.5f) ? 0.0f : v_stn;

                const float I_gpi = (0.4f + mean1 * -0.8f) + s_stn * 0.6f;
                v_gpi = 0.8f * v_gpi + 0.2f * I_gpi;
                const float s_gpi = (v_gpi >= 0.5f) ? 1.0f : 0.0f;
                v_gpi = (v_gpi >= 0.5f) ? 0.0f : v_gpi;

                const float gate = mean1 - s_gpi;   // wave-uniform

                // lane ((i&1)*32 + s) latches step i*32+s's gate
                const int latch = ((i & 1) << 5) | s;
                gate_reg = (lane == latch) ? gate : gate_reg;
            }

            if (i & 1) {
                // store 64 gates for steps (i-1)*32 .. i*32+31
                const int t0 = (i - 1) * S;
                out[(size_t)(t0 + lane) * B + b] = gate_reg;
            }

            __syncthreads();
        }
    } else {
        // ================= PRODUCERS (waves 1..8) =================
        const float4 w1 = *(const float4*)(Wd1 + 4 * lane);
        const float4 w2 = *(const float4*)(Wd2 + 4 * lane);
        const float* n1b = nd1 + (size_t)b * 128 + 2 * lane;
        const float* n2b = nd2 + (size_t)b * 128 + 2 * lane;
        const int p0 = (wv - 1) * 4;   // this wave covers steps p0..p0+3

        // stage(c, bf): compute I for this wave's 4 steps of chunk c into
        // lds_I[bf]. Loads issued first (8 in flight), then the EXACT
        // R2..R5 op sequence (contract off, fma dot) — bit-exact.
        auto stage = [&](int c, int bf) {
            const int tbase = c * S;
            float2 a1[4], a2[4];
#pragma unroll
            for (int j = 0; j < 4; ++j) {
                const int t = tbase + p0 + j;
                a1[j] = *(const float2*)(n1b + (size_t)t * TSTRIDE);
                a2[j] = *(const float2*)(n2b + (size_t)t * TSTRIDE);
            }
#pragma unroll
            for (int j = 0; j < 4; ++j) {
                const int s = p0 + j;
                const int t = tbase + s;
                const float xx = lds_x[t][0], xy = lds_x[t][1];
                const float dop = lds_d[t];

                const float m1 = 1.0f + dop * 0.5f;
                const float m2 = 1.0f - dop * 0.3f;

                const float dot1a = __builtin_fmaf(xy, w1.y, xx * w1.x);
                const float dot1b = __builtin_fmaf(xy, w1.w, xx * w1.z);
                const float dot2a = __builtin_fmaf(xy, w2.y, xx * w2.x);
                const float dot2b = __builtin_fmaf(xy, w2.w, xx * w2.z);

                float4 I;
                I.x = dot1a * m1 + a1[j].x * 0.1f;
                I.y = dot1b * m1 + a1[j].y * 0.1f;
                I.z = dot2a * m2 + a2[j].x * 0.1f;
                I.w = dot2b * m2 + a2[j].y * 0.1f;

                *(float4*)&lds_I[bf][s][lane][0] = I;
            }
        };

        // prologue B: chunks 0 and 1
        stage(0, 0);
        stage(1, 1);
        __syncthreads();

        for (int i = 0; i < NCH; ++i) {
            if (i + 2 < NCH) stage(i + 2, (i + 2) % 3);
            __syncthreads();
        }
    }
}

extern "C" void kernel_launch(void* const* d_in, const int* in_sizes, int n_in,
                              void* d_out, int out_size, void* d_ws, size_t ws_size,
                              hipStream_t stream) {
    const float* x    = (const float*)d_in[0];
    const float* dopa = (const float*)d_in[1];
    // d_in[2] = rpe — unused by the reference
    const float* Wd1  = (const float*)d_in[3];
    const float* Wd2  = (const float*)d_in[4];
    const float* nd1  = (const float*)d_in[5];
    const float* nd2  = (const float*)d_in[6];
    float* out = (float*)d_out;

    bg_kernel<<<dim3(256), dim3(576), 0, stream>>>(x, dopa, Wd1, Wd2, nd1, nd2, out);
}